// Round 6
// baseline (783.609 us; speedup 1.0000x reference)
//
#include <hip/hip_runtime.h>

#define KVOX 12000
#define TPTS 35
#define FIN  7
#define DD   10
#define HH   400
#define WW   352
#define CO   128
#define EPSBN 1e-3f
#define NCELL (DD * HH * WW)              // 1,408,000 cells
#define TOTALF4 ((size_t)NCELL * 32)      // 45,056,000 float4 = 720.9 MB

#define FILLB 2048                        // fill grid: pure-store, poison-fill pattern
#define CB    3000                        // compute grid: 4 waves = 4 voxels/block

static_assert(CB * 4 == KVOX, "grid covers voxels exactly");

// ---- kernel 1: zero the output. Identical access pattern to the rocclr
// poison fill that measures 6.25 TB/s (460us for 2.88GB) -> ~115us for 721MB.
__global__ __launch_bounds__(256) void fill_out(float4* __restrict__ o4)
{
    const float4 z = make_float4(0.f, 0.f, 0.f, 0.f);
    const size_t stride = (size_t)FILLB * 256;
    for (size_t i = (size_t)blockIdx.x * 256 + threadIdx.x; i < TOTALF4; i += stride)
        o4[i] = z;
}

// ---- kernel 2: VFE compute (wave per voxel) + direct atomic scatter ----
// Spill-free rewrite (no pw[35] array). Valid-only loops; invalid points
// contribute analytic constants (zero input row => p = BN(relu(bias)),
// computed with the identical fma sequence -> bit-equal).
// R4 bug fixed here: reference voxelwise = max_t(cat*mask), so invalid t
// contribute an exact 0 to the per-channel max -> voxA needs the 0-clamp
// when nvalid < TPTS (R4 omitted it: absmax 0.81 fail).
__global__ __launch_bounds__(256) void vfe_scatter(
    const float* __restrict__ feat,
    const float* __restrict__ w1, const float* __restrict__ b1,
    const float* __restrict__ g1, const float* __restrict__ be1,
    const float* __restrict__ m1, const float* __restrict__ v1,
    const float* __restrict__ w2, const float* __restrict__ b2,
    const float* __restrict__ g2, const float* __restrict__ be2,
    const float* __restrict__ m2, const float* __restrict__ v2,
    const int* __restrict__ coord,
    float* __restrict__ out)
{
    const int tid  = threadIdx.x;
    const int wv   = tid >> 6;        // wave in block: 0..3
    const int lane = tid & 63;
    const int k    = blockIdx.x * 4 + wv;

    __shared__ __align__(16) float sxp[4][TPTS][8];    // padded point features
    __shared__ __align__(16) float spwm[4][TPTS][16];  // masked stage-1 pointwise
    __shared__ __align__(16) float sagg[4][16];        // stage-1 aggregate

    const float* fk = feat + (size_t)k * (TPTS * FIN);

    // stage features into LDS, rows padded to 8 (b128 reads later)
    for (int i = lane; i < TPTS * FIN; i += 64)
        sxp[wv][i / FIN][i % FIN] = fk[i];
    if (lane < TPTS) sxp[wv][lane][FIN] = 0.0f;

    // zero spwm: invalid rows stay zero (masked); valid rows overwritten below.
    // Same-wave instruction order guarantees zero-then-overwrite visibility.
    for (int i = lane; i < TPTS * 16; i += 64)
        ((float*)spwm[wv])[i] = 0.0f;

    // per-point validity straight from global (L1-hot after staging)
    bool pred = false;
    if (lane < TPTS) {
        const float* row = fk + lane * FIN;
        float mx = row[0];
        #pragma unroll
        for (int f = 1; f < FIN; ++f) mx = fmaxf(mx, row[f]);
        pred = (mx != 0.0f);
    }
    const unsigned long long bal = __ballot(pred);   // wave-uniform
    const int nvalid = __popcll(bal);

    // ---- stage 1: dense(7->16)+relu+BN, valid points only, no pw[] array ----
    if (lane < 16) {
        const int u = lane;
        float w1c[8];
        #pragma unroll
        for (int f = 0; f < FIN; ++f) w1c[f] = w1[f * 16 + u];
        w1c[FIN] = 0.0f;
        const float b     = b1[u];
        const float scale = g1[u] * rsqrtf(v1[u] + EPSBN);
        const float shift = be1[u] - m1[u] * scale;

        float agg = -INFINITY;
        unsigned long long m = bal;
        while (m) {
            const int t = __builtin_ctzll(m); m &= m - 1;   // uniform branch
            const float4 xa = *(const float4*)&sxp[wv][t][0];  // runtime-t b128
            const float4 xb = *(const float4*)&sxp[wv][t][4];
            float d = b;
            d = fmaf(xa.x, w1c[0], d); d = fmaf(xa.y, w1c[1], d);
            d = fmaf(xa.z, w1c[2], d); d = fmaf(xa.w, w1c[3], d);
            d = fmaf(xb.x, w1c[4], d); d = fmaf(xb.y, w1c[5], d);
            d = fmaf(xb.z, w1c[6], d); d = fmaf(xb.w, w1c[7], d);
            d = fmaxf(d, 0.0f);
            const float p = fmaf(d, scale, shift);
            agg = fmaxf(agg, p);
            spwm[wv][t][u] = p;                  // mk==1 here
        }
        if (nvalid < TPTS) {
            // invalid row: x==0 -> d==b exactly -> p = BN(relu(b)), same fma seq
            const float cu = fmaf(fmaxf(b, 0.0f), scale, shift);
            agg = fmaxf(agg, cu);
        }
        sagg[wv][u] = agg;
    }

    // ---- stage 2: dense(32->64)+relu+BN, channel v per lane, valid-only ----
    {
        const int v = lane;
        float w2c[32];
        #pragma unroll
        for (int u = 0; u < 32; ++u) w2c[u] = w2[u * 64 + v];
        const float b     = b2[v];
        const float scale = g2[v] * rsqrtf(v2[v] + EPSBN);
        const float shift = be2[v] - m2[v] * scale;

        // aggdot = sum_u agg[u] * w2c[16+u]  (t-independent)
        float aggdot = 0.0f;
        {
            const float4* ar = (const float4*)&sagg[wv][0];
            #pragma unroll
            for (int q = 0; q < 4; ++q) {
                const float4 a = ar[q];
                aggdot = fmaf(a.x, w2c[16 + 4 * q + 0], aggdot);
                aggdot = fmaf(a.y, w2c[16 + 4 * q + 1], aggdot);
                aggdot = fmaf(a.z, w2c[16 + 4 * q + 2], aggdot);
                aggdot = fmaf(a.w, w2c[16 + 4 * q + 3], aggdot);
            }
        }
        const float d0 = aggdot + b;

        float aggV = -INFINITY;                  // max over valid t of p
        unsigned long long m = bal;
        while (m) {
            const int t = __builtin_ctzll(m); m &= m - 1;   // uniform branch
            const float4* xr = (const float4*)&spwm[wv][t][0];
            float d = d0;
            #pragma unroll
            for (int q = 0; q < 4; ++q) {
                const float4 xv = xr[q];         // runtime-t b128
                d = fmaf(xv.x, w2c[4 * q + 0], d);
                d = fmaf(xv.y, w2c[4 * q + 1], d);
                d = fmaf(xv.z, w2c[4 * q + 2], d);
                d = fmaf(xv.w, w2c[4 * q + 3], d);
            }
            d = fmaxf(d, 0.0f);
            const float p = fmaf(d, scale, shift);
            aggV = fmaxf(aggV, p);
        }

        // voxA = max_t(pw2 * mask): invalid t contribute exact 0 to the max
        float voxA;
        if (nvalid == 0)          voxA = 0.0f;
        else if (nvalid < TPTS)   voxA = fmaxf(aggV, 0.0f);   // R4 fix
        else                      voxA = aggV;

        float aggAll = aggV;
        if (nvalid < TPTS) {
            // invalid row fully masked to zero -> d==b -> p = BN(relu(b))
            const float cv = fmaf(fmaxf(b, 0.0f), scale, shift);
            aggAll = fmaxf(aggAll, cv);
        }
        float voxB;
        if (nvalid == 0)          voxB = 0.0f;
        else if (nvalid < TPTS)   voxB = fmaxf(aggAll, 0.0f);
        else                      voxB = aggAll;

        // direct scatter (duplicates accumulate; out zeroed by fill_out)
        const int4 c = ((const int4*)coord)[k];
        const int loc = (((c.x * DD + c.y) * HH + c.z) * WW + c.w);
        float* o = out + (size_t)loc * CO;
        atomicAdd(o + v,      voxA);
        atomicAdd(o + 64 + v, voxB);
    }
}

extern "C" void kernel_launch(void* const* d_in, const int* in_sizes, int n_in,
                              void* d_out, int out_size, void* d_ws, size_t ws_size,
                              hipStream_t stream) {
    const float* feat = (const float*)d_in[0];
    const float* w1   = (const float*)d_in[1];
    const float* b1   = (const float*)d_in[2];
    const float* g1   = (const float*)d_in[3];
    const float* be1  = (const float*)d_in[4];
    const float* m1   = (const float*)d_in[5];
    const float* v1   = (const float*)d_in[6];
    const float* w2   = (const float*)d_in[7];
    const float* b2   = (const float*)d_in[8];
    const float* g2   = (const float*)d_in[9];
    const float* be2  = (const float*)d_in[10];
    const float* m2   = (const float*)d_in[11];
    const float* v2   = (const float*)d_in[12];
    const int*   coord = (const int*)d_in[13];
    float* out = (float*)d_out;

    // Two launches, no workspace: pure fill (poison-fill pattern, ~115us),
    // then spill-free compute + direct atomic scatter.
    fill_out<<<FILLB, 256, 0, stream>>>((float4*)out);
    vfe_scatter<<<CB, 256, 0, stream>>>(feat, w1, b1, g1, be1, m1, v1,
                                        w2, b2, g2, be2, m2, v2, coord, out);
}

// Round 7
// 752.385 us; speedup vs baseline: 1.0415x; 1.0415x over previous
//
#include <hip/hip_runtime.h>

#define KVOX 12000
#define TPTS 35
#define FIN  7
#define DD   10
#define HH   400
#define WW   352
#define CO   128
#define EPSBN 1e-3f
#define NCELL (DD * HH * WW)              // 1,408,000 cells
#define TOTALF4 ((size_t)NCELL * 32)      // 45,056,000 float4 = 720.9 MB

#define FILLB 2200                        // fill blocks, contiguous chunk each
#define F4PB  20480                       // float4 per block = 320 KB contiguous
#define CB    3000                        // compute grid: 4 waves = 4 voxels/block

static_assert((size_t)FILLB * F4PB == TOTALF4, "fill covers out exactly");
static_assert(F4PB % 256 == 0, "whole iterations per thread");
static_assert(CB * 4 == KVOX, "grid covers voxels exactly");

// ---- kernel 1: zero the output, BLOCK-CONTIGUOUS addressing ----
// R6 post-mortem: all previous fills (R0/R1/R3/R6) used wide grid-stride
// (8-12MB stride; every wave sweeps all ~344 2MB-pages of the buffer) and
// all measured ~2.5 TB/s, while rocclr's fill of the same class of buffer
// measures 6.3 TB/s. This version gives each block one contiguous 320KB
// chunk (stride 4KB within it): page-local, fully coalesced. Single-variable
// A/B vs R6 — compute kernel below is byte-identical to the R6-verified one.
__global__ __launch_bounds__(256) void fill_out(float4* __restrict__ o4)
{
    const float4 z = make_float4(0.f, 0.f, 0.f, 0.f);
    float4* p = o4 + (size_t)blockIdx.x * F4PB + threadIdx.x;
    #pragma unroll 8
    for (int it = 0; it < F4PB / 256; ++it)     // 80 stores, 4KB apart
        p[it * 256] = z;
}

// ---- kernel 2: VFE compute (wave per voxel) + direct atomic scatter ----
// Verbatim from R6 (harness-verified, absmax 0.0039). Valid-only loops;
// invalid points contribute analytic constants (zero input row => p =
// BN(relu(bias)), identical fma sequence -> bit-equal). voxA carries the
// 0-clamp when nvalid < TPTS (reference: max_t(cat*mask)).
__global__ __launch_bounds__(256) void vfe_scatter(
    const float* __restrict__ feat,
    const float* __restrict__ w1, const float* __restrict__ b1,
    const float* __restrict__ g1, const float* __restrict__ be1,
    const float* __restrict__ m1, const float* __restrict__ v1,
    const float* __restrict__ w2, const float* __restrict__ b2,
    const float* __restrict__ g2, const float* __restrict__ be2,
    const float* __restrict__ m2, const float* __restrict__ v2,
    const int* __restrict__ coord,
    float* __restrict__ out)
{
    const int tid  = threadIdx.x;
    const int wv   = tid >> 6;        // wave in block: 0..3
    const int lane = tid & 63;
    const int k    = blockIdx.x * 4 + wv;

    __shared__ __align__(16) float sxp[4][TPTS][8];    // padded point features
    __shared__ __align__(16) float spwm[4][TPTS][16];  // masked stage-1 pointwise
    __shared__ __align__(16) float sagg[4][16];        // stage-1 aggregate

    const float* fk = feat + (size_t)k * (TPTS * FIN);

    // stage features into LDS, rows padded to 8 (b128 reads later)
    for (int i = lane; i < TPTS * FIN; i += 64)
        sxp[wv][i / FIN][i % FIN] = fk[i];
    if (lane < TPTS) sxp[wv][lane][FIN] = 0.0f;

    // zero spwm: invalid rows stay zero (masked); valid rows overwritten below.
    for (int i = lane; i < TPTS * 16; i += 64)
        ((float*)spwm[wv])[i] = 0.0f;

    // per-point validity straight from global (L1-hot after staging)
    bool pred = false;
    if (lane < TPTS) {
        const float* row = fk + lane * FIN;
        float mx = row[0];
        #pragma unroll
        for (int f = 1; f < FIN; ++f) mx = fmaxf(mx, row[f]);
        pred = (mx != 0.0f);
    }
    const unsigned long long bal = __ballot(pred);   // wave-uniform
    const int nvalid = __popcll(bal);

    // ---- stage 1: dense(7->16)+relu+BN, valid points only ----
    if (lane < 16) {
        const int u = lane;
        float w1c[8];
        #pragma unroll
        for (int f = 0; f < FIN; ++f) w1c[f] = w1[f * 16 + u];
        w1c[FIN] = 0.0f;
        const float b     = b1[u];
        const float scale = g1[u] * rsqrtf(v1[u] + EPSBN);
        const float shift = be1[u] - m1[u] * scale;

        float agg = -INFINITY;
        unsigned long long m = bal;
        while (m) {
            const int t = __builtin_ctzll(m); m &= m - 1;   // uniform branch
            const float4 xa = *(const float4*)&sxp[wv][t][0];  // runtime-t b128
            const float4 xb = *(const float4*)&sxp[wv][t][4];
            float d = b;
            d = fmaf(xa.x, w1c[0], d); d = fmaf(xa.y, w1c[1], d);
            d = fmaf(xa.z, w1c[2], d); d = fmaf(xa.w, w1c[3], d);
            d = fmaf(xb.x, w1c[4], d); d = fmaf(xb.y, w1c[5], d);
            d = fmaf(xb.z, w1c[6], d); d = fmaf(xb.w, w1c[7], d);
            d = fmaxf(d, 0.0f);
            const float p = fmaf(d, scale, shift);
            agg = fmaxf(agg, p);
            spwm[wv][t][u] = p;                  // mk==1 here
        }
        if (nvalid < TPTS) {
            // invalid row: x==0 -> d==b exactly -> p = BN(relu(b)), same fma seq
            const float cu = fmaf(fmaxf(b, 0.0f), scale, shift);
            agg = fmaxf(agg, cu);
        }
        sagg[wv][u] = agg;
    }

    // ---- stage 2: dense(32->64)+relu+BN, channel v per lane, valid-only ----
    {
        const int v = lane;
        float w2c[32];
        #pragma unroll
        for (int u = 0; u < 32; ++u) w2c[u] = w2[u * 64 + v];
        const float b     = b2[v];
        const float scale = g2[v] * rsqrtf(v2[v] + EPSBN);
        const float shift = be2[v] - m2[v] * scale;

        // aggdot = sum_u agg[u] * w2c[16+u]  (t-independent)
        float aggdot = 0.0f;
        {
            const float4* ar = (const float4*)&sagg[wv][0];
            #pragma unroll
            for (int q = 0; q < 4; ++q) {
                const float4 a = ar[q];
                aggdot = fmaf(a.x, w2c[16 + 4 * q + 0], aggdot);
                aggdot = fmaf(a.y, w2c[16 + 4 * q + 1], aggdot);
                aggdot = fmaf(a.z, w2c[16 + 4 * q + 2], aggdot);
                aggdot = fmaf(a.w, w2c[16 + 4 * q + 3], aggdot);
            }
        }
        const float d0 = aggdot + b;

        float aggV = -INFINITY;                  // max over valid t of p
        unsigned long long m = bal;
        while (m) {
            const int t = __builtin_ctzll(m); m &= m - 1;   // uniform branch
            const float4* xr = (const float4*)&spwm[wv][t][0];
            float d = d0;
            #pragma unroll
            for (int q = 0; q < 4; ++q) {
                const float4 xv = xr[q];         // runtime-t b128
                d = fmaf(xv.x, w2c[4 * q + 0], d);
                d = fmaf(xv.y, w2c[4 * q + 1], d);
                d = fmaf(xv.z, w2c[4 * q + 2], d);
                d = fmaf(xv.w, w2c[4 * q + 3], d);
            }
            d = fmaxf(d, 0.0f);
            const float p = fmaf(d, scale, shift);
            aggV = fmaxf(aggV, p);
        }

        // voxA = max_t(pw2 * mask): invalid t contribute exact 0 to the max
        float voxA;
        if (nvalid == 0)          voxA = 0.0f;
        else if (nvalid < TPTS)   voxA = fmaxf(aggV, 0.0f);
        else                      voxA = aggV;

        float aggAll = aggV;
        if (nvalid < TPTS) {
            // invalid row fully masked to zero -> d==b -> p = BN(relu(b))
            const float cv = fmaf(fmaxf(b, 0.0f), scale, shift);
            aggAll = fmaxf(aggAll, cv);
        }
        float voxB;
        if (nvalid == 0)          voxB = 0.0f;
        else if (nvalid < TPTS)   voxB = fmaxf(aggAll, 0.0f);
        else                      voxB = aggAll;

        // direct scatter (duplicates accumulate; out zeroed by fill_out)
        const int4 c = ((const int4*)coord)[k];
        const int loc = (((c.x * DD + c.y) * HH + c.z) * WW + c.w);
        float* o = out + (size_t)loc * CO;
        atomicAdd(o + v,      voxA);
        atomicAdd(o + 64 + v, voxB);
    }
}

extern "C" void kernel_launch(void* const* d_in, const int* in_sizes, int n_in,
                              void* d_out, int out_size, void* d_ws, size_t ws_size,
                              hipStream_t stream) {
    const float* feat = (const float*)d_in[0];
    const float* w1   = (const float*)d_in[1];
    const float* b1   = (const float*)d_in[2];
    const float* g1   = (const float*)d_in[3];
    const float* be1  = (const float*)d_in[4];
    const float* m1   = (const float*)d_in[5];
    const float* v1   = (const float*)d_in[6];
    const float* w2   = (const float*)d_in[7];
    const float* b2   = (const float*)d_in[8];
    const float* g2   = (const float*)d_in[9];
    const float* be2  = (const float*)d_in[10];
    const float* m2   = (const float*)d_in[11];
    const float* v2   = (const float*)d_in[12];
    const int*   coord = (const int*)d_in[13];
    float* out = (float*)d_out;

    // Two launches, no workspace: block-contiguous fill, then the R6-verified
    // compute + direct atomic scatter.
    fill_out<<<FILLB, 256, 0, stream>>>((float4*)out);
    vfe_scatter<<<CB, 256, 0, stream>>>(feat, w1, b1, g1, be1, m1, v1,
                                        w2, b2, g2, be2, m2, v2, coord, out);
}

// Round 8
// 733.323 us; speedup vs baseline: 1.0686x; 1.0260x over previous
//
#include <hip/hip_runtime.h>

#define KVOX 12000
#define TPTS 35
#define FIN  7
#define DD   10
#define HH   400
#define WW   352
#define CO   128
#define EPSBN 1e-3f
#define NCELL (DD * HH * WW)              // 1,408,000 cells
#define OUTB  ((size_t)NCELL * CO * 4)    // 720,896,000 bytes = exact output size

#define CB    3000                        // compute grid: 4 waves = 4 voxels/block
static_assert(CB * 4 == KVOX, "grid covers voxels exactly");

// ---- VFE compute (wave per voxel) + direct atomic scatter ----
// Verbatim from R6/R7 (harness-verified, absmax 0.0039). Valid-only loops;
// invalid points contribute analytic constants (zero input row => p =
// BN(relu(bias)), identical fma sequence -> bit-equal). voxA carries the
// 0-clamp when nvalid < TPTS (reference: max_t(cat*mask)).
//
// R7 post-mortem note: the output zero-fill is now hipMemsetAsync (rocclr's
// fillBufferAligned, measured 6.27 TB/s in this exact graph) instead of our
// hand-rolled fills, which never exceeded ~2.7 TB/s in any structure
// (wide-stride R1/R6, contiguous R7, fused R0, write_bg R3).
__global__ __launch_bounds__(256) void vfe_scatter(
    const float* __restrict__ feat,
    const float* __restrict__ w1, const float* __restrict__ b1,
    const float* __restrict__ g1, const float* __restrict__ be1,
    const float* __restrict__ m1, const float* __restrict__ v1,
    const float* __restrict__ w2, const float* __restrict__ b2,
    const float* __restrict__ g2, const float* __restrict__ be2,
    const float* __restrict__ m2, const float* __restrict__ v2,
    const int* __restrict__ coord,
    float* __restrict__ out)
{
    const int tid  = threadIdx.x;
    const int wv   = tid >> 6;        // wave in block: 0..3
    const int lane = tid & 63;
    const int k    = blockIdx.x * 4 + wv;

    __shared__ __align__(16) float sxp[4][TPTS][8];    // padded point features
    __shared__ __align__(16) float spwm[4][TPTS][16];  // masked stage-1 pointwise
    __shared__ __align__(16) float sagg[4][16];        // stage-1 aggregate

    const float* fk = feat + (size_t)k * (TPTS * FIN);

    // stage features into LDS, rows padded to 8 (b128 reads later)
    for (int i = lane; i < TPTS * FIN; i += 64)
        sxp[wv][i / FIN][i % FIN] = fk[i];
    if (lane < TPTS) sxp[wv][lane][FIN] = 0.0f;

    // zero spwm: invalid rows stay zero (masked); valid rows overwritten below.
    for (int i = lane; i < TPTS * 16; i += 64)
        ((float*)spwm[wv])[i] = 0.0f;

    // per-point validity straight from global (L1-hot after staging)
    bool pred = false;
    if (lane < TPTS) {
        const float* row = fk + lane * FIN;
        float mx = row[0];
        #pragma unroll
        for (int f = 1; f < FIN; ++f) mx = fmaxf(mx, row[f]);
        pred = (mx != 0.0f);
    }
    const unsigned long long bal = __ballot(pred);   // wave-uniform
    const int nvalid = __popcll(bal);

    // ---- stage 1: dense(7->16)+relu+BN, valid points only ----
    if (lane < 16) {
        const int u = lane;
        float w1c[8];
        #pragma unroll
        for (int f = 0; f < FIN; ++f) w1c[f] = w1[f * 16 + u];
        w1c[FIN] = 0.0f;
        const float b     = b1[u];
        const float scale = g1[u] * rsqrtf(v1[u] + EPSBN);
        const float shift = be1[u] - m1[u] * scale;

        float agg = -INFINITY;
        unsigned long long m = bal;
        while (m) {
            const int t = __builtin_ctzll(m); m &= m - 1;   // uniform branch
            const float4 xa = *(const float4*)&sxp[wv][t][0];  // runtime-t b128
            const float4 xb = *(const float4*)&sxp[wv][t][4];
            float d = b;
            d = fmaf(xa.x, w1c[0], d); d = fmaf(xa.y, w1c[1], d);
            d = fmaf(xa.z, w1c[2], d); d = fmaf(xa.w, w1c[3], d);
            d = fmaf(xb.x, w1c[4], d); d = fmaf(xb.y, w1c[5], d);
            d = fmaf(xb.z, w1c[6], d); d = fmaf(xb.w, w1c[7], d);
            d = fmaxf(d, 0.0f);
            const float p = fmaf(d, scale, shift);
            agg = fmaxf(agg, p);
            spwm[wv][t][u] = p;                  // mk==1 here
        }
        if (nvalid < TPTS) {
            // invalid row: x==0 -> d==b exactly -> p = BN(relu(b)), same fma seq
            const float cu = fmaf(fmaxf(b, 0.0f), scale, shift);
            agg = fmaxf(agg, cu);
        }
        sagg[wv][u] = agg;
    }

    // ---- stage 2: dense(32->64)+relu+BN, channel v per lane, valid-only ----
    {
        const int v = lane;
        float w2c[32];
        #pragma unroll
        for (int u = 0; u < 32; ++u) w2c[u] = w2[u * 64 + v];
        const float b     = b2[v];
        const float scale = g2[v] * rsqrtf(v2[v] + EPSBN);
        const float shift = be2[v] - m2[v] * scale;

        // aggdot = sum_u agg[u] * w2c[16+u]  (t-independent)
        float aggdot = 0.0f;
        {
            const float4* ar = (const float4*)&sagg[wv][0];
            #pragma unroll
            for (int q = 0; q < 4; ++q) {
                const float4 a = ar[q];
                aggdot = fmaf(a.x, w2c[16 + 4 * q + 0], aggdot);
                aggdot = fmaf(a.y, w2c[16 + 4 * q + 1], aggdot);
                aggdot = fmaf(a.z, w2c[16 + 4 * q + 2], aggdot);
                aggdot = fmaf(a.w, w2c[16 + 4 * q + 3], aggdot);
            }
        }
        const float d0 = aggdot + b;

        float aggV = -INFINITY;                  // max over valid t of p
        unsigned long long m = bal;
        while (m) {
            const int t = __builtin_ctzll(m); m &= m - 1;   // uniform branch
            const float4* xr = (const float4*)&spwm[wv][t][0];
            float d = d0;
            #pragma unroll
            for (int q = 0; q < 4; ++q) {
                const float4 xv = xr[q];         // runtime-t b128
                d = fmaf(xv.x, w2c[4 * q + 0], d);
                d = fmaf(xv.y, w2c[4 * q + 1], d);
                d = fmaf(xv.z, w2c[4 * q + 2], d);
                d = fmaf(xv.w, w2c[4 * q + 3], d);
            }
            d = fmaxf(d, 0.0f);
            const float p = fmaf(d, scale, shift);
            aggV = fmaxf(aggV, p);
        }

        // voxA = max_t(pw2 * mask): invalid t contribute exact 0 to the max
        float voxA;
        if (nvalid == 0)          voxA = 0.0f;
        else if (nvalid < TPTS)   voxA = fmaxf(aggV, 0.0f);
        else                      voxA = aggV;

        float aggAll = aggV;
        if (nvalid < TPTS) {
            // invalid row fully masked to zero -> d==b -> p = BN(relu(b))
            const float cv = fmaf(fmaxf(b, 0.0f), scale, shift);
            aggAll = fmaxf(aggAll, cv);
        }
        float voxB;
        if (nvalid == 0)          voxB = 0.0f;
        else if (nvalid < TPTS)   voxB = fmaxf(aggAll, 0.0f);
        else                      voxB = aggAll;

        // direct scatter (duplicates accumulate; out zeroed by the memset)
        const int4 c = ((const int4*)coord)[k];
        const int loc = (((c.x * DD + c.y) * HH + c.z) * WW + c.w);
        float* o = out + (size_t)loc * CO;
        atomicAdd(o + v,      voxA);
        atomicAdd(o + 64 + v, voxB);
    }
}

extern "C" void kernel_launch(void* const* d_in, const int* in_sizes, int n_in,
                              void* d_out, int out_size, void* d_ws, size_t ws_size,
                              hipStream_t stream) {
    const float* feat = (const float*)d_in[0];
    const float* w1   = (const float*)d_in[1];
    const float* b1   = (const float*)d_in[2];
    const float* g1   = (const float*)d_in[3];
    const float* be1  = (const float*)d_in[4];
    const float* m1   = (const float*)d_in[5];
    const float* v1   = (const float*)d_in[6];
    const float* w2   = (const float*)d_in[7];
    const float* b2   = (const float*)d_in[8];
    const float* g2   = (const float*)d_in[9];
    const float* be2  = (const float*)d_in[10];
    const float* m2   = (const float*)d_in[11];
    const float* v2   = (const float*)d_in[12];
    const int*   coord = (const int*)d_in[13];
    float* out = (float*)d_out;

    // Zero the output via the runtime's fill (rocclr fillBufferAligned:
    // measured 6.27 TB/s in this exact graph — our hand-rolled fills cap at
    // ~2.7 TB/s). R0 evidence: out_size is a BYTE count (its memset of
    // out_size*4 wrote exactly 4x the output). Use the exact constant,
    // clamped by out_size interpreted as bytes for safety.
    size_t fill_bytes = OUTB;
    if ((size_t)out_size >= OUTB) {           // out_size in bytes (expected)
        fill_bytes = OUTB;
    }
    hipMemsetAsync(d_out, 0, fill_bytes, stream);
    vfe_scatter<<<CB, 256, 0, stream>>>(feat, w1, b1, g1, be1, m1, v1,
                                        w2, b2, g2, be2, m2, v2, coord, out);
}